// Round 1
// baseline (643.038 us; speedup 1.0000x reference)
//
#include <hip/hip_runtime.h>

typedef __bf16 bf16;
typedef __attribute__((ext_vector_type(8))) __bf16 bf16x8;
typedef __attribute__((ext_vector_type(4))) __bf16 bf16x4;
typedef __attribute__((ext_vector_type(4))) float f32x4;

#define MFMA16(a, b, c) __builtin_amdgcn_mfma_f32_16x16x32_bf16((a), (b), (c), 0, 0, 0)

// ---------------------------------------------------------------------------
// Transpose + fp32->bf16 convert: W[K][N] (row-major) -> Wt[N][K] bf16
// ---------------------------------------------------------------------------
__global__ void transpose_cvt(const float* __restrict__ W, bf16* __restrict__ Wt,
                              int K, int N) {
    __shared__ bf16 tile[32][33];
    int tx = threadIdx.x, ty = threadIdx.y;   // 32 x 8
    int n0 = blockIdx.x * 32, k0 = blockIdx.y * 32;
#pragma unroll
    for (int j = 0; j < 4; ++j)
        tile[ty + j * 8][tx] = (bf16)W[(size_t)(k0 + ty + j * 8) * N + n0 + tx];
    __syncthreads();
#pragma unroll
    for (int j = 0; j < 4; ++j)
        Wt[(size_t)(n0 + ty + j * 8) * K + k0 + tx] = tile[tx][ty + j * 8];
}

// ---------------------------------------------------------------------------
// GEMM: C[M][N] = A[M][K] * Bt[N][K]^T   (MFMA 16x16x32 bf16, f32 accum)
// A either fp32 (converted on the fly) or bf16. Optional fused RoPE epilogue
// (hd=128, S=2048), optional f32 output.
// Tiles: 128x128, BK=64, 256 threads = 4 waves, each wave 64x64.
// ---------------------------------------------------------------------------
template <bool A_F32, bool DO_ROPE, bool OUT_F32>
__global__ __launch_bounds__(256) void gemm_bt(
    const void* __restrict__ Ain, const bf16* __restrict__ Bt,
    void* __restrict__ Cout, const float* __restrict__ cosb,
    const float* __restrict__ sinb, int Mm, int Nn, int Kk) {
    __shared__ bf16 As[128][72];   // +8 pad
    __shared__ bf16 Bs[128][72];
    int tid = threadIdx.x;
    int lane = tid & 63, wid = tid >> 6;
    int lr = lane & 15, lg = lane >> 4;
    int m0 = blockIdx.y * 128, n0 = blockIdx.x * 128;
    int wr = wid >> 1, wc = wid & 1;

    f32x4 acc[4][4] = {};

    const int nk = Kk >> 6;
    for (int kt = 0; kt < nk; ++kt) {
        int k0 = kt << 6;
        // ---- stage A tile (128 x 64) ----
        if constexpr (A_F32) {
            const float* A = (const float*)Ain;
#pragma unroll
            for (int i = 0; i < 8; ++i) {
                int slot = tid + i * 256;
                int row = slot >> 4, c4 = (slot & 15) << 2;
                f32x4 v = *reinterpret_cast<const f32x4*>(
                    A + (size_t)(m0 + row) * Kk + k0 + c4);
                bf16x4 h;
                h[0] = (bf16)v[0]; h[1] = (bf16)v[1];
                h[2] = (bf16)v[2]; h[3] = (bf16)v[3];
                *reinterpret_cast<bf16x4*>(&As[row][c4]) = h;
            }
        } else {
            const bf16* A = (const bf16*)Ain;
#pragma unroll
            for (int i = 0; i < 4; ++i) {
                int slot = tid + i * 256;
                int row = slot >> 3, c8 = (slot & 7) << 3;
                *reinterpret_cast<bf16x8*>(&As[row][c8]) =
                    *reinterpret_cast<const bf16x8*>(
                        A + (size_t)(m0 + row) * Kk + k0 + c8);
            }
        }
        // ---- stage Bt tile (128 x 64) ----
#pragma unroll
        for (int i = 0; i < 4; ++i) {
            int slot = tid + i * 256;
            int row = slot >> 3, c8 = (slot & 7) << 3;
            *reinterpret_cast<bf16x8*>(&Bs[row][c8]) =
                *reinterpret_cast<const bf16x8*>(
                    Bt + (size_t)(n0 + row) * Kk + k0 + c8);
        }
        __syncthreads();
        // ---- compute ----
#pragma unroll
        for (int kk = 0; kk < 2; ++kk) {
            bf16x8 af[4], bfr[4];
#pragma unroll
            for (int mi = 0; mi < 4; ++mi)
                af[mi] = *reinterpret_cast<const bf16x8*>(
                    &As[wr * 64 + mi * 16 + lr][kk * 32 + lg * 8]);
#pragma unroll
            for (int ni = 0; ni < 4; ++ni)
                bfr[ni] = *reinterpret_cast<const bf16x8*>(
                    &Bs[wc * 64 + ni * 16 + lr][kk * 32 + lg * 8]);
#pragma unroll
            for (int mi = 0; mi < 4; ++mi)
#pragma unroll
                for (int ni = 0; ni < 4; ++ni)
                    acc[mi][ni] = MFMA16(af[mi], bfr[ni], acc[mi][ni]);
        }
        __syncthreads();
    }

    // ---- epilogue: C/D layout col = lane&15, row = (lane>>4)*4 + r ----
    int m_base = m0 + wr * 64, n_base = n0 + wc * 64;
#pragma unroll
    for (int mi = 0; mi < 4; ++mi) {
#pragma unroll
        for (int ni = 0; ni < 4; ++ni) {
            f32x4 v = acc[mi][ni];
            int gn = n_base + ni * 16 + lr;
            if constexpr (DO_ROPE) {
                int d = gn & 127, p = d >> 1;
                bool ev = ((d & 1) == 0);
#pragma unroll
                for (int r = 0; r < 4; ++r) {
                    int gm = m_base + mi * 16 + lg * 4 + r;
                    int s = gm & 2047;
                    float cc = cosb[s * 64 + p];
                    float ss = sinb[s * 64 + p];
                    float oth = __shfl_xor(v[r], 1);
                    v[r] = ev ? (v[r] * cc - oth * ss) : (oth * ss + v[r] * cc);
                }
            }
            if constexpr (OUT_F32) {
                float* C = (float*)Cout;
#pragma unroll
                for (int r = 0; r < 4; ++r)
                    C[(size_t)(m_base + mi * 16 + lg * 4 + r) * Nn + gn] = v[r];
            } else {
                bf16* C = (bf16*)Cout;
#pragma unroll
                for (int r = 0; r < 4; ++r)
                    C[(size_t)(m_base + mi * 16 + lg * 4 + r) * Nn + gn] =
                        (bf16)v[r];
            }
        }
    }
}

// ---------------------------------------------------------------------------
// Causal flash attention, GQA. Qp:(B,S,H,hd) Kp/Vp:(B,S,HKV,hd), all bf16.
// Block = 256 thr = 4 waves, each wave owns 16 q-rows; q-tile = 64 rows.
// KBLK = 32. Grid: (S/64, H, B).
// ---------------------------------------------------------------------------
__global__ __launch_bounds__(256) void attn_kernel(
    const bf16* __restrict__ Qp, const bf16* __restrict__ Kp,
    const bf16* __restrict__ Vp, bf16* __restrict__ Ao) {
    const int S = 2048, H = 16, HKV = 4, HD = 128;
    __shared__ bf16 Klds[32][136];     // [s][d], +8 pad
    __shared__ bf16 Vlds[128][40];     // [d][s] transposed, +8 pad
    __shared__ bf16 Plds[4][16][40];   // per-wave P staging

    int tid = threadIdx.x, lane = tid & 63, wid = tid >> 6;
    int lr = lane & 15, lg = lane >> 4;
    int qt = blockIdx.x, h = blockIdx.y, b = blockIdx.z;
    int hkv = h >> 2;
    int q0 = qt * 64 + wid * 16;

    // Q fragments in registers: A-layout row=lane&15, k=(lane>>4)*8+j
    bf16x8 qf[4];
    {
        const bf16* qb = Qp + ((size_t)(b * S + q0 + lr) * H + h) * HD;
#pragma unroll
        for (int ks = 0; ks < 4; ++ks)
            qf[ks] = *reinterpret_cast<const bf16x8*>(qb + ks * 32 + lg * 8);
    }

    f32x4 O[8] = {};
    float m_run[4] = {-3e38f, -3e38f, -3e38f, -3e38f};
    float l_run[4] = {0.f, 0.f, 0.f, 0.f};
    const float scale = 0.08838834764831845f;  // 1/sqrt(128)

    int nkb = qt * 2 + 2;  // causal: tiles with s0 <= qt*64+63
    for (int kb = 0; kb < nkb; ++kb) {
        int s0 = kb * 32;
        // stage K tile (32 x 128) row-major
#pragma unroll
        for (int i = 0; i < 2; ++i) {
            int slot = tid + i * 256;
            int row = slot >> 4, c8 = (slot & 15) << 3;
            *reinterpret_cast<bf16x8*>(&Klds[row][c8]) =
                *reinterpret_cast<const bf16x8*>(
                    Kp + ((size_t)(b * S + s0 + row) * HKV + hkv) * HD + c8);
        }
        // stage V tile transposed: Vlds[d][s]
#pragma unroll
        for (int i = 0; i < 2; ++i) {
            int slot = tid + i * 256;
            int row = slot >> 4, c8 = (slot & 15) << 3;
            bf16x8 vv = *reinterpret_cast<const bf16x8*>(
                Vp + ((size_t)(b * S + s0 + row) * HKV + hkv) * HD + c8);
#pragma unroll
            for (int j = 0; j < 8; ++j) Vlds[c8 + j][row] = vv[j];
        }
        __syncthreads();

        // scores: S = Q * K^T  (two 16-wide col tiles)
        float p[2][4];
#pragma unroll
        for (int nt = 0; nt < 2; ++nt) {
            f32x4 sc = {};
#pragma unroll
            for (int ks = 0; ks < 4; ++ks) {
                bf16x8 kf = *reinterpret_cast<const bf16x8*>(
                    &Klds[nt * 16 + lr][ks * 32 + lg * 8]);
                sc = MFMA16(qf[ks], kf, sc);
            }
            int cs = s0 + nt * 16 + lr;
#pragma unroll
            for (int r = 0; r < 4; ++r) {
                int rs = q0 + lg * 4 + r;
                p[nt][r] = (cs <= rs) ? sc[r] * scale : -1e30f;
            }
        }
        // online softmax (row stats across 16 lanes of the group)
        float alpha[4];
#pragma unroll
        for (int r = 0; r < 4; ++r) {
            float mx = fmaxf(p[0][r], p[1][r]);
#pragma unroll
            for (int off = 1; off < 16; off <<= 1)
                mx = fmaxf(mx, __shfl_xor(mx, off));
            float mnew = fmaxf(m_run[r], mx);
            alpha[r] = __expf(m_run[r] - mnew);
            m_run[r] = mnew;
            p[0][r] = __expf(p[0][r] - mnew);
            p[1][r] = __expf(p[1][r] - mnew);
            float rs = p[0][r] + p[1][r];
#pragma unroll
            for (int off = 1; off < 16; off <<= 1) rs += __shfl_xor(rs, off);
            l_run[r] = l_run[r] * alpha[r] + rs;
        }
        // P -> LDS (C-layout -> A-layout via per-wave staging)
#pragma unroll
        for (int nt = 0; nt < 2; ++nt)
#pragma unroll
            for (int r = 0; r < 4; ++r)
                Plds[wid][lg * 4 + r][nt * 16 + lr] = (bf16)p[nt][r];
        // rescale O
#pragma unroll
        for (int n2 = 0; n2 < 8; ++n2)
#pragma unroll
            for (int r = 0; r < 4; ++r) O[n2][r] *= alpha[r];
        // PV: O += P * V
        bf16x8 pf = *reinterpret_cast<const bf16x8*>(&Plds[wid][lr][lg * 8]);
#pragma unroll
        for (int n2 = 0; n2 < 8; ++n2) {
            bf16x8 vf =
                *reinterpret_cast<const bf16x8*>(&Vlds[n2 * 16 + lr][lg * 8]);
            O[n2] = MFMA16(pf, vf, O[n2]);
        }
        __syncthreads();
    }

    // epilogue: normalize and store (B,S,H,hd)
#pragma unroll
    for (int r = 0; r < 4; ++r) {
        float inv = 1.0f / l_run[r];
        size_t gm = (size_t)(b * S + q0 + lg * 4 + r);
#pragma unroll
        for (int n2 = 0; n2 < 8; ++n2)
            Ao[(gm * H + h) * HD + n2 * 16 + lr] = (bf16)(O[n2][r] * inv);
    }
}

// ---------------------------------------------------------------------------
extern "C" void kernel_launch(void* const* d_in, const int* in_sizes, int n_in,
                              void* d_out, int out_size, void* d_ws,
                              size_t ws_size, hipStream_t stream) {
    const float* q = (const float*)d_in[0];
    const float* k = (const float*)d_in[1];
    const float* v = (const float*)d_in[2];
    // d_in[3] = mask (causal tril; handled analytically)
    const float* fc = (const float*)d_in[4];
    const float* fs = (const float*)d_in[5];
    const float* Wq = (const float*)d_in[6];
    const float* Wk = (const float*)d_in[7];
    const float* Wv = (const float*)d_in[8];
    const float* Wo = (const float*)d_in[9];

    char* ws = (char*)d_ws;
    bf16* Wq_t = (bf16*)(ws + 0);          //  8,388,608 B
    bf16* Wk_t = (bf16*)(ws + 8388608);    //  2,097,152
    bf16* Wv_t = (bf16*)(ws + 10485760);   //  2,097,152
    bf16* Wo_t = (bf16*)(ws + 12582912);   //  8,388,608
    bf16* Qp   = (bf16*)(ws + 20971520);   // 16,777,216
    bf16* Kp   = (bf16*)(ws + 37748736);   //  4,194,304
    bf16* Vp   = (bf16*)(ws + 41943040);   //  4,194,304
    bf16* Ao   = (bf16*)(ws + 46137344);   // 16,777,216  (end 62,914,560)

    dim3 tb(32, 8);
    transpose_cvt<<<dim3(64, 64), tb, 0, stream>>>(Wq, Wq_t, 2048, 2048);
    transpose_cvt<<<dim3(16, 64), tb, 0, stream>>>(Wk, Wk_t, 2048, 512);
    transpose_cvt<<<dim3(16, 64), tb, 0, stream>>>(Wv, Wv_t, 2048, 512);
    transpose_cvt<<<dim3(64, 64), tb, 0, stream>>>(Wo, Wo_t, 2048, 2048);

    // Q projection + RoPE -> Qp (4096 x 2048 bf16)
    gemm_bt<true, true, false><<<dim3(16, 32), 256, 0, stream>>>(
        (const void*)q, Wq_t, (void*)Qp, fc, fs, 4096, 2048, 2048);
    // K projection + RoPE -> Kp (4096 x 512)
    gemm_bt<true, true, false><<<dim3(4, 32), 256, 0, stream>>>(
        (const void*)k, Wk_t, (void*)Kp, fc, fs, 4096, 512, 2048);
    // V projection -> Vp (4096 x 512)
    gemm_bt<true, false, false><<<dim3(4, 32), 256, 0, stream>>>(
        (const void*)v, Wv_t, (void*)Vp, fc, fs, 4096, 512, 2048);

    attn_kernel<<<dim3(32, 16, 2), 256, 0, stream>>>(Qp, Kp, Vp, Ao);

    // Output projection -> d_out fp32 (4096 x 2048)
    gemm_bt<false, false, true><<<dim3(16, 32), 256, 0, stream>>>(
        (const void*)Ao, Wo_t, d_out, fc, fs, 4096, 2048, 2048);
}